// Round 14
// baseline (241.361 us; speedup 1.0000x reference)
//
#include <hip/hip_runtime.h>

// ---- f64 DCT magnitudes (0.5*cos(m*pi/16)); f32 casts match np.asarray(D,f32).
#define C0 0.35355339059327373
#define C1 0.49039264020161522
#define C2 0.46193976625564337
#define C3 0.41573480615127262
#define C4 0.35355339059327379
#define C5 0.27778511650980109
#define C6 0.19134171618254489
#define C7 0.09754516100806413

#define F0 ((float)C0)
#define F1 ((float)C1)
#define F2 ((float)C2)
#define F3 ((float)C3)
#define F4 ((float)C4)
#define F5 ((float)C5)
#define F6 ((float)C6)
#define F7 ((float)C7)

typedef float f32x2 __attribute__((ext_vector_type(2)));

__device__ __forceinline__ f32x2 mk2(float x, float y) { f32x2 v; v.x = x; v.y = y; return v; }
__device__ __forceinline__ f32x2 bc2(float x) { return mk2(x, x); }
__device__ __forceinline__ f32x2 mul2(f32x2 a, f32x2 b) {
#pragma clang fp contract(off)
    return a * b;
}
__device__ __forceinline__ f32x2 add2(f32x2 a, f32x2 b) {
#pragma clang fp contract(off)
    return a + b;
}
__device__ __forceinline__ f32x2 sub2(f32x2 a, f32x2 b) {
#pragma clang fp contract(off)
    return a - b;
}
#define FMA2(a, b, c) __builtin_elementwise_fma((a), (b), (c))

// Row-pair table: DP[p][j] = { DF[2p][j], DF[2p+1][j] } of the f32 DCT matrix.
__device__ constexpr f32x2 DP[4][8] = {
    { {F0, F1}, {F0, F3}, {F0, F5}, {F0, F7}, {F0,-F7}, {F0,-F5}, {F0,-F3}, {F0,-F1} },
    { {F2, F3}, {F6,-F7}, {-F6,-F1}, {-F2,-F5}, {-F2, F5}, {-F6, F1}, {F6, F7}, {F2,-F3} },
    { {F4, F5}, {-F4,-F1}, {-F4, F7}, {F4, F3}, {F4,-F3}, {-F4,-F7}, {-F4, F1}, {F4,-F5} },
    { {F6, F7}, {-F2,-F5}, {F2, F3}, {-F6,-F1}, {-F6, F1}, {F2,-F3}, {-F2, F5}, {F6,-F7} },
};

// ---- exact-f32 scalar helpers (boundary-critical paths).
__device__ __forceinline__ float mulf(float a, float b) {
#pragma clang fp contract(off)
    return a * b;
}
__device__ __forceinline__ float addf(float a, float b) {
#pragma clang fp contract(off)
    return a + b;
}
__device__ __forceinline__ float subf(float a, float b) {
#pragma clang fp contract(off)
    return a - b;
}
__device__ __forceinline__ float divf(float a, float b) {
#pragma clang fp contract(off)
    return a / b;
}

// ---- packed fast IDCT butterfly: out[n] = sum_u D[u][n]*in[u]. Precision
// non-critical (affects only +-1-level final pixel rounding = 0.0078).
__device__ __forceinline__ void inv8f2(float m[8]) {
    const f32x2 m0 = bc2(m[0]), m1 = bc2(m[1]), m2 = bc2(m[2]), m3 = bc2(m[3]),
                m4 = bc2(m[4]), m5 = bc2(m[5]), m6 = bc2(m[6]), m7 = bc2(m[7]);
    const f32x2 a01 = FMA2(mk2(F0,F0), m0, FMA2(mk2(F2,F6), m2,
                      FMA2(mk2(F0,-F0), m4, mul2(mk2(F6,-F2), m6))));
    const f32x2 a23 = FMA2(mk2(F0,F0), m0, FMA2(mk2(-F6,-F2), m2,
                      FMA2(mk2(-F0,F0), m4, mul2(mk2(F2,-F6), m6))));
    const f32x2 o01 = FMA2(mk2(F1,F3), m1, FMA2(mk2(F3,-F7), m3,
                      FMA2(mk2(F5,-F1), m5, mul2(mk2(F7,-F5), m7))));
    const f32x2 o23 = FMA2(mk2(F5,F7), m1, FMA2(mk2(-F1,-F5), m3,
                      FMA2(mk2(F7,F3), m5, mul2(mk2(F3,-F1), m7))));
    const f32x2 r01 = add2(a01, o01);   // {m0', m1'}
    const f32x2 r76 = sub2(a01, o01);   // {m7', m6'}
    const f32x2 r23 = add2(a23, o23);   // {m2', m3'}
    const f32x2 r54 = sub2(a23, o23);   // {m5', m4'}
    m[0] = r01[0]; m[1] = r01[1]; m[7] = r76[0]; m[6] = r76[1];
    m[2] = r23[0]; m[3] = r23[1]; m[5] = r54[0]; m[4] = r54[1];
}

// 8x8 transpose across the 8 lane-groups: new[reg r, grp g] = old[reg g, grp r].
__device__ __forceinline__ void transpose8f(float m[8], int g) {
#pragma unroll
    for (int s = 1; s <= 4; s <<= 1) {
        const bool up = (g & s) != 0;
#pragma unroll
        for (int j = 0; j < 8; ++j) {
            if ((j & s) == 0) {
                const int jj = j | s;
                float send = up ? m[j] : m[jj];
                float recv = __shfl_xor(send, s << 3, 64);
                m[j]  = up ? recv : m[j];
                m[jj] = up ? m[jj] : recv;
            }
        }
    }
}

__global__ __launch_bounds__(256) void jpeg_k(const float* __restrict__ img,
                                              const float* __restrict__ QY,
                                              const float* __restrict__ QC,
                                              float* __restrict__ out) {
    __shared__ float lds_q[2][64];
    __shared__ float lds_rq[2][64];
    {
        const int t = threadIdx.x;
        if (t < 128) {
            const int cc = t >> 6, idx = t & 63;
            const float q = (cc ? QC : QY)[idx];
            lds_q[cc][idx]  = q;
            lds_rq[cc][idx] = divf(1.0f, q);   // exact RN(1/q), once per block
        }
    }
    __syncthreads();

    const int lane = threadIdx.x & 63;
    const int g  = lane >> 3;
    const int wv = threadIdx.x >> 6;
    const size_t plane = 1048576;  // 1024*1024
    const int row = blockIdx.y * 8 + g;
    const int col = (blockIdx.x * 4 + wv) * 64 + (lane & 7) * 8;
    const size_t base = (size_t)blockIdx.z * (3 * plane) + (size_t)row * 1024 + (size_t)col;

    const float* pR = img + base;
    const float4 r0 = *reinterpret_cast<const float4*>(pR);
    const float4 r1 = *reinterpret_cast<const float4*>(pR + 4);
    const float4 g0 = *reinterpret_cast<const float4*>(pR + plane);
    const float4 g1 = *reinterpret_cast<const float4*>(pR + plane + 4);
    const float4 b0 = *reinterpret_cast<const float4*>(pR + 2 * plane);
    const float4 b1 = *reinterpret_cast<const float4*>(pR + 2 * plane + 4);
    const float Rf[8] = {r0.x, r0.y, r0.z, r0.w, r1.x, r1.y, r1.z, r1.w};
    const float Gf[8] = {g0.x, g0.y, g0.z, g0.w, g1.x, g1.y, g1.z, g1.w};
    const float Bf[8] = {b0.x, b0.y, b0.z, b0.w, b1.x, b1.y, b1.z, b1.w};

    // Exact f32 rgb->ycbcr, PACKED by pixel pairs (identical per-component op
    // order as scalar; must stay bit-exact: feeds quant boundary decisions).
    float Yi[8], Cbi[8], Cri[8];
#pragma unroll
    for (int p = 0; p < 4; ++p) {
        const f32x2 R2 = mk2(Rf[2*p], Rf[2*p+1]);
        const f32x2 G2 = mk2(Gf[2*p], Gf[2*p+1]);
        const f32x2 B2 = mk2(Bf[2*p], Bf[2*p+1]);
        const f32x2 xr = mul2(add2(mul2(R2, bc2(0.5f)), bc2(0.5f)), bc2(255.0f));
        const f32x2 xg = mul2(add2(mul2(G2, bc2(0.5f)), bc2(0.5f)), bc2(255.0f));
        const f32x2 xb = mul2(add2(mul2(B2, bc2(0.5f)), bc2(0.5f)), bc2(255.0f));
        const f32x2 y2 = add2(add2(add2(mul2(bc2((float)0.256788), xr),
                                        mul2(bc2((float)0.504129), xg)),
                                   mul2(bc2((float)0.0979059), xb)), bc2(16.0f));
        const f32x2 cb2 = add2(sub2(sub2(bc2(128.0f), mul2(bc2((float)0.148224), xr)),
                                    mul2(bc2((float)0.290992), xg)),
                               mul2(bc2((float)0.439216), xb));
        const f32x2 cr2 = sub2(sub2(add2(bc2(128.0f), mul2(bc2((float)0.439216), xr)),
                                    mul2(bc2((float)0.367788), xg)),
                               mul2(bc2((float)0.0714275), xb));
        Yi[2*p]  = rintf(y2[0]);  Yi[2*p+1]  = rintf(y2[1]);
        Cbi[2*p] = rintf(cb2[0]); Cbi[2*p+1] = rintf(cb2[1]);
        Cri[2*p] = rintf(cr2[0]); Cri[2*p+1] = rintf(cr2[1]);
    }

    float rec0[8], rec1[8], rec2[8];

#pragma unroll 1
    for (int c = 0; c < 3; ++c) {
        const int qi = (c == 0) ? 0 : 1;
        const float* qp  = &lds_q[qi][g * 8];
        const float* rqp = &lds_rq[qi][g * 8];

        float Mrow[8];
#pragma unroll
        for (int j = 0; j < 8; ++j) {
            const float v = (c == 0) ? Yi[j] : ((c == 1) ? Cbi[j] : Cri[j]);
            Mrow[j] = subf(v, 128.0f);
        }

        // Stage 1 (packed over i-pairs; per-component chain == R13's FMA chain):
        float t[8];
#pragma unroll
        for (int p = 0; p < 4; ++p) {
            f32x2 acc = bc2(0.0f);
#pragma unroll
            for (int j = 0; j < 8; ++j) acc = FMA2(DP[p][j], bc2(Mrow[j]), acc);
            t[2*p] = acc[0]; t[2*p+1] = acc[1];
        }
        transpose8f(t, g);   // row layout: t[k] = tmp[i=g, k]

        // Stage 2 (packed over l-pairs) + band-hedged quantization.
        float m[8];
#pragma unroll
        for (int p = 0; p < 4; ++p) {
            f32x2 z = bc2(0.0f);
#pragma unroll
            for (int k = 0; k < 8; ++k) z = FMA2(DP[p][k], bc2(t[k]), z);
            const f32x2 rq2 = mk2(rqp[2*p], rqp[2*p+1]);
            const f32x2 tt  = mul2(z, rq2);
#pragma unroll
            for (int h = 0; h < 2; ++h) {
                const float ttc = tt[h];
                const float qc  = qp[2*p + h];
                const float r   = rintf(ttc);
                const float d   = subf(ttc, r);
                const float dist = fabsf(fabsf(d) - 0.5f);
                // Band >> any plausible accumulation-order delta (max ~1e-5):
                const float eps = __builtin_fmaf(fabsf(ttc), 8e-6f, 1.5e-5f);
                m[2*p + h] = (dist < eps) ? mulf(addf(r, copysignf(0.5f, d)), qc)
                                          : mulf(r, qc);
            }
        }

        // IDCT + transpose-back, from row layout m[l] = Zq[g][l]:
        //   inv -> (Zq D)[g][n];  T -> (Zq D)[j][g];
        //   inv -> (Dt Zq D)[a][g] = rec_x[a][g] = out_P[g][a].   (store-ready)
        inv8f2(m);
        transpose8f(m, g);
        inv8f2(m);

#pragma unroll
        for (int j = 0; j < 8; ++j) {
            if (c == 0) rec0[j] = m[j];
            else if (c == 1) rec1[j] = m[j];
            else rec2[j] = m[j];
        }
    }

    // Fast final color stage, packed (continuous path: 1e-7 deviation ok).
    float fr[8], fg[8], fb[8];
    const f32x2 S2 = bc2(2.0f / 255.0f);
#pragma unroll
    for (int p = 0; p < 4; ++p) {
        const f32x2 y2  = add2(mk2(rec0[2*p], rec0[2*p+1]), bc2(112.0f));
        const f32x2 cb2 = mk2(rec1[2*p], rec1[2*p+1]);
        const f32x2 cr2 = mk2(rec2[2*p], rec2[2*p+1]);
        const f32x2 Rt = FMA2(bc2(1.16438f), y2,
                         FMA2(bc2(1.59603f), cr2, mul2(bc2(3.01124e-07f), cb2)));
        const f32x2 Gt = FMA2(bc2(1.16438f), y2,
                         -FMA2(bc2(0.391763f), cb2, mul2(bc2(0.812968f), cr2)));
        const f32x2 Bt = FMA2(bc2(1.16438f), y2,
                         FMA2(bc2(2.01723f), cb2, mul2(bc2(3.05426e-06f), cr2)));
        const f32x2 Rv = mk2(rintf(Rt[0]), rintf(Rt[1]));
        const f32x2 Gv = mk2(rintf(Gt[0]), rintf(Gt[1]));
        const f32x2 Bv = mk2(rintf(Bt[0]), rintf(Bt[1]));
        const f32x2 fr2 = FMA2(Rv, S2, bc2(-1.0f));
        const f32x2 fg2 = FMA2(Gv, S2, bc2(-1.0f));
        const f32x2 fb2 = FMA2(Bv, S2, bc2(-1.0f));
        fr[2*p] = fr2[0]; fr[2*p+1] = fr2[1];
        fg[2*p] = fg2[0]; fg[2*p+1] = fg2[1];
        fb[2*p] = fb2[0]; fb[2*p+1] = fb2[1];
    }

    float* o = out + base;
    *reinterpret_cast<float4*>(o)                 = make_float4(fr[0], fr[1], fr[2], fr[3]);
    *reinterpret_cast<float4*>(o + 4)             = make_float4(fr[4], fr[5], fr[6], fr[7]);
    *reinterpret_cast<float4*>(o + plane)         = make_float4(fg[0], fg[1], fg[2], fg[3]);
    *reinterpret_cast<float4*>(o + plane + 4)     = make_float4(fg[4], fg[5], fg[6], fg[7]);
    *reinterpret_cast<float4*>(o + 2 * plane)     = make_float4(fb[0], fb[1], fb[2], fb[3]);
    *reinterpret_cast<float4*>(o + 2 * plane + 4) = make_float4(fb[4], fb[5], fb[6], fb[7]);
}

extern "C" void kernel_launch(void* const* d_in, const int* in_sizes, int n_in,
                              void* d_out, int out_size, void* d_ws, size_t ws_size,
                              hipStream_t stream) {
    const float* img = (const float*)d_in[0];
    const float* QY  = (const float*)d_in[1];
    const float* QC  = (const float*)d_in[2];
    float* out = (float*)d_out;
    const int B = in_sizes[0] / (3 * 1024 * 1024);
    dim3 grid(1024 / 256, 1024 / 8, B);
    jpeg_k<<<grid, dim3(256), 0, stream>>>(img, QY, QC, out);
}

// Round 15
// 48.717 us; speedup vs baseline: 4.9544x; 4.9544x over previous
//
#include <hip/hip_runtime.h>

// ---- f64 DCT magnitudes (0.5*cos(m*pi/16)); f32 casts match np.asarray(D,f32).
#define C0 0.35355339059327373
#define C1 0.49039264020161522
#define C2 0.46193976625564337
#define C3 0.41573480615127262
#define C5 0.27778511650980109
#define C6 0.19134171618254489
#define C7 0.09754516100806413

#define F0 ((float)C0)
#define F1 ((float)C1)
#define F2 ((float)C2)
#define F3 ((float)C3)
#define F5 ((float)C5)
#define F6 ((float)C6)
#define F7 ((float)C7)

// ---- exact-f32 scalar helpers (boundary-critical paths).
__device__ __forceinline__ float mulf(float a, float b) {
#pragma clang fp contract(off)
    return a * b;
}
__device__ __forceinline__ float addf(float a, float b) {
#pragma clang fp contract(off)
    return a + b;
}
__device__ __forceinline__ float subf(float a, float b) {
#pragma clang fp contract(off)
    return a - b;
}
__device__ __forceinline__ float divf(float a, float b) {
#pragma clang fp contract(off)
    return a / b;
}

// ---- forward DCT-II butterfly: m[i] <- sum_n D[i][n]*m[n]. Accumulation
// order differs from ref's chain by <= ~10 ulps -> covered by the hedge band.
__device__ __forceinline__ void fwd8(float m[8]) {
    const float e0 = m[0] + m[7], e1 = m[1] + m[6], e2 = m[2] + m[5], e3 = m[3] + m[4];
    const float o0 = m[0] - m[7], o1 = m[1] - m[6], o2 = m[2] - m[5], o3 = m[3] - m[4];
    m[0] = F0 * (e0 + e1 + e2 + e3);
    m[4] = F0 * (e0 - e1 - e2 + e3);
    m[2] = F2*e0 + F6*e1 - F6*e2 - F2*e3;
    m[6] = F6*e0 - F2*e1 + F2*e2 - F6*e3;
    m[1] = F1*o0 + F3*o1 + F5*o2 + F7*o3;
    m[3] = F3*o0 - F7*o1 - F1*o2 - F5*o3;
    m[5] = F5*o0 - F1*o1 + F7*o2 + F3*o3;
    m[7] = F7*o0 - F5*o1 + F3*o2 - F1*o3;
}

// ---- fast f32 IDCT butterfly: out[n] = sum_u D[u][n]*in[u]. Precision
// non-critical (affects only +-1-level final pixel rounding = 0.0078).
__device__ __forceinline__ void inv8f(float m[8]) {
    const float a0 = F0*m[0] + F2*m[2] + F0*m[4] + F6*m[6];
    const float a1 = F0*m[0] + F6*m[2] - F0*m[4] - F2*m[6];
    const float a2 = F0*m[0] - F6*m[2] - F0*m[4] + F2*m[6];
    const float a3 = F0*m[0] - F2*m[2] + F0*m[4] - F6*m[6];
    const float o0 = F1*m[1] + F3*m[3] + F5*m[5] + F7*m[7];
    const float o1 = F3*m[1] - F7*m[3] - F1*m[5] - F5*m[7];
    const float o2 = F5*m[1] - F1*m[3] + F7*m[5] + F3*m[7];
    const float o3 = F7*m[1] - F5*m[3] + F3*m[5] - F1*m[7];
    m[0] = a0 + o0; m[7] = a0 - o0;
    m[1] = a1 + o1; m[6] = a1 - o1;
    m[2] = a2 + o2; m[5] = a2 - o2;
    m[3] = a3 + o3; m[4] = a3 - o3;
}

// 8x8 transpose across the 8 lane-groups (2-shuffle variant: moves select work
// from the saturated VALU pipe onto the DS pipe).
__device__ __forceinline__ void transpose8f(float m[8], int g) {
#pragma unroll
    for (int s = 1; s <= 4; s <<= 1) {
        const bool up = (g & s) != 0;
#pragma unroll
        for (int j = 0; j < 8; ++j) {
            if ((j & s) == 0) {
                const int jj = j | s;
                const float yj  = __shfl_xor(m[j],  s << 3, 64);
                const float yjj = __shfl_xor(m[jj], s << 3, 64);
                m[j]  = up ? yjj : m[j];
                m[jj] = up ? m[jj] : yj;
            }
        }
    }
}

// One channel: P-integer values (in[j] at column j, row g) -> reconstructed
// pixels rec[a] = out_P[g][a] (store-ready).
__device__ __forceinline__ void do_channel(const float in[8], const float* qp,
                                           const float* rqp, int g, float rec[8]) {
    float t[8];
#pragma unroll
    for (int j = 0; j < 8; ++j) t[j] = subf(in[j], 128.0f);

    fwd8(t);             // stage 1: tmp[i, k=g]
    transpose8f(t, g);   // row layout: t[k] = tmp[i=g, k]
    fwd8(t);             // stage 2: z[g, l]

    // Band-hedged quantization (band >> any accumulation-order delta).
#pragma unroll
    for (int l = 0; l < 8; ++l) {
        const float q  = qp[l];
        const float tt = mulf(t[l], rqp[l]);
        const float r  = rintf(tt);
        const float d  = subf(tt, r);
        const float dist = fabsf(fabsf(d) - 0.5f);
        const float eps = __builtin_fmaf(fabsf(tt), 8e-6f, 1.5e-5f);
        t[l] = (dist < eps) ? mulf(addf(r, copysignf(0.5f, d)), q)
                            : mulf(r, q);
    }

    // IDCT + transpose-back, from row layout t[l] = Zq[g][l]:
    //   inv -> (Zq D)[g][n];  T -> (Zq D)[j][g];
    //   inv -> (Dt Zq D)[a][g] = rec_x[a][g] = out_P[g][a].
    inv8f(t);
    transpose8f(t, g);
    inv8f(t);
#pragma unroll
    for (int j = 0; j < 8; ++j) rec[j] = t[j];
}

__global__ __launch_bounds__(256) void jpeg_k(const float* __restrict__ img,
                                              const float* __restrict__ QY,
                                              const float* __restrict__ QC,
                                              float* __restrict__ out) {
    __shared__ float lds_q[2][64];
    __shared__ float lds_rq[2][64];
    {
        const int t = threadIdx.x;
        if (t < 128) {
            const int cc = t >> 6, idx = t & 63;
            const float q = (cc ? QC : QY)[idx];
            lds_q[cc][idx]  = q;
            lds_rq[cc][idx] = divf(1.0f, q);   // exact RN(1/q), once per block
        }
    }
    __syncthreads();

    const int lane = threadIdx.x & 63;
    const int g  = lane >> 3;
    const int wv = threadIdx.x >> 6;
    const size_t plane = 1048576;  // 1024*1024
    const int row = blockIdx.y * 8 + g;
    const int col = (blockIdx.x * 4 + wv) * 64 + (lane & 7) * 8;
    const size_t base = (size_t)blockIdx.z * (3 * plane) + (size_t)row * 1024 + (size_t)col;

    const float* pR = img + base;
    const float4 r0 = *reinterpret_cast<const float4*>(pR);
    const float4 r1 = *reinterpret_cast<const float4*>(pR + 4);
    const float4 g0 = *reinterpret_cast<const float4*>(pR + plane);
    const float4 g1 = *reinterpret_cast<const float4*>(pR + plane + 4);
    const float4 b0 = *reinterpret_cast<const float4*>(pR + 2 * plane);
    const float4 b1 = *reinterpret_cast<const float4*>(pR + 2 * plane + 4);
    const float Rf[8] = {r0.x, r0.y, r0.z, r0.w, r1.x, r1.y, r1.z, r1.w};
    const float Gf[8] = {g0.x, g0.y, g0.z, g0.w, g1.x, g1.y, g1.z, g1.w};
    const float Bf[8] = {b0.x, b0.y, b0.z, b0.w, b1.x, b1.y, b1.z, b1.w};

    // Exact f32 rgb->ycbcr (literal numpy op order, rintf = RNE = np.round).
    // Must be bit-exact: integer Y/Cb/Cr feed the quant boundary decisions.
    float Yi[8], Cbi[8], Cri[8];
#pragma unroll
    for (int j = 0; j < 8; ++j) {
        const float xr = mulf(addf(mulf(Rf[j], 0.5f), 0.5f), 255.0f);
        const float xg = mulf(addf(mulf(Gf[j], 0.5f), 0.5f), 255.0f);
        const float xb = mulf(addf(mulf(Bf[j], 0.5f), 0.5f), 255.0f);
        Yi[j]  = rintf(addf(addf(addf(mulf((float)0.256788, xr), mulf((float)0.504129, xg)),
                                 mulf((float)0.0979059, xb)), 16.0f));
        Cbi[j] = rintf(addf(subf(subf(128.0f, mulf((float)0.148224, xr)),
                                 mulf((float)0.290992, xg)), mulf((float)0.439216, xb)));
        Cri[j] = rintf(subf(subf(addf(128.0f, mulf((float)0.439216, xr)),
                                 mulf((float)0.367788, xg)), mulf((float)0.0714275, xb)));
    }

    // Fully unrolled channels (no runtime-c selects / predicated writebacks).
    float rec0[8], rec1[8], rec2[8];
    do_channel(Yi,  &lds_q[0][g * 8], &lds_rq[0][g * 8], g, rec0);
    do_channel(Cbi, &lds_q[1][g * 8], &lds_rq[1][g * 8], g, rec1);
    do_channel(Cri, &lds_q[1][g * 8], &lds_rq[1][g * 8], g, rec2);

    // Fast final color stage (continuous path: 1e-7-level deviation ok).
    float fr[8], fg[8], fb[8];
    const float S = 2.0f / 255.0f;
#pragma unroll
    for (int j = 0; j < 8; ++j) {
        const float y  = rec0[j] + 112.0f;          // (+128) - 16
        const float cb = rec1[j];                    // (+128) - 128
        const float cr = rec2[j];
        const float Rv = rintf(__builtin_fmaf(1.16438f, y,
                               __builtin_fmaf(1.59603f, cr, 3.01124e-07f * cb)));
        const float Gv = rintf(__builtin_fmaf(1.16438f, y,
                               -__builtin_fmaf(0.391763f, cb, 0.812968f * cr)));
        const float Bv = rintf(__builtin_fmaf(1.16438f, y,
                               __builtin_fmaf(2.01723f, cb, 3.05426e-06f * cr)));
        fr[j] = __builtin_fmaf(Rv, S, -1.0f);
        fg[j] = __builtin_fmaf(Gv, S, -1.0f);
        fb[j] = __builtin_fmaf(Bv, S, -1.0f);
    }

    float* o = out + base;
    *reinterpret_cast<float4*>(o)                 = make_float4(fr[0], fr[1], fr[2], fr[3]);
    *reinterpret_cast<float4*>(o + 4)             = make_float4(fr[4], fr[5], fr[6], fr[7]);
    *reinterpret_cast<float4*>(o + plane)         = make_float4(fg[0], fg[1], fg[2], fg[3]);
    *reinterpret_cast<float4*>(o + plane + 4)     = make_float4(fg[4], fg[5], fg[6], fg[7]);
    *reinterpret_cast<float4*>(o + 2 * plane)     = make_float4(fb[0], fb[1], fb[2], fb[3]);
    *reinterpret_cast<float4*>(o + 2 * plane + 4) = make_float4(fb[4], fb[5], fb[6], fb[7]);
}

extern "C" void kernel_launch(void* const* d_in, const int* in_sizes, int n_in,
                              void* d_out, int out_size, void* d_ws, size_t ws_size,
                              hipStream_t stream) {
    const float* img = (const float*)d_in[0];
    const float* QY  = (const float*)d_in[1];
    const float* QC  = (const float*)d_in[2];
    float* out = (float*)d_out;
    const int B = in_sizes[0] / (3 * 1024 * 1024);
    dim3 grid(1024 / 256, 1024 / 8, B);
    jpeg_k<<<grid, dim3(256), 0, stream>>>(img, QY, QC, out);
}

// Round 16
// 46.942 us; speedup vs baseline: 5.1417x; 1.0378x over previous
//
#include <hip/hip_runtime.h>

// ---- f64 DCT magnitudes (0.5*cos(m*pi/16)); f32 casts match np.asarray(D,f32).
#define C0 0.35355339059327373
#define C1 0.49039264020161522
#define C2 0.46193976625564337
#define C3 0.41573480615127262
#define C5 0.27778511650980109
#define C6 0.19134171618254489
#define C7 0.09754516100806413

#define F0 ((float)C0)
#define F1 ((float)C1)
#define F2 ((float)C2)
#define F3 ((float)C3)
#define F5 ((float)C5)
#define F6 ((float)C6)
#define F7 ((float)C7)

// ---- exact-f32 scalar helpers (boundary-critical paths).
__device__ __forceinline__ float mulf(float a, float b) {
#pragma clang fp contract(off)
    return a * b;
}
__device__ __forceinline__ float addf(float a, float b) {
#pragma clang fp contract(off)
    return a + b;
}
__device__ __forceinline__ float subf(float a, float b) {
#pragma clang fp contract(off)
    return a - b;
}
__device__ __forceinline__ float divf(float a, float b) {
#pragma clang fp contract(off)
    return a / b;
}

// ---- forward DCT-II butterfly: m[i] <- sum_n D[i][n]*m[n]. Accumulation
// order differs from ref's chain by <= ~10 ulps -> covered by the hedge band.
__device__ __forceinline__ void fwd8(float m[8]) {
    const float e0 = m[0] + m[7], e1 = m[1] + m[6], e2 = m[2] + m[5], e3 = m[3] + m[4];
    const float o0 = m[0] - m[7], o1 = m[1] - m[6], o2 = m[2] - m[5], o3 = m[3] - m[4];
    m[0] = F0 * (e0 + e1 + e2 + e3);
    m[4] = F0 * (e0 - e1 - e2 + e3);
    m[2] = F2*e0 + F6*e1 - F6*e2 - F2*e3;
    m[6] = F6*e0 - F2*e1 + F2*e2 - F6*e3;
    m[1] = F1*o0 + F3*o1 + F5*o2 + F7*o3;
    m[3] = F3*o0 - F7*o1 - F1*o2 - F5*o3;
    m[5] = F5*o0 - F1*o1 + F7*o2 + F3*o3;
    m[7] = F7*o0 - F5*o1 + F3*o2 - F1*o3;
}

// ---- fast f32 IDCT butterfly: out[n] = sum_u D[u][n]*in[u]. Precision
// non-critical (affects only +-1-level final pixel rounding = 0.0078).
__device__ __forceinline__ void inv8f(float m[8]) {
    const float a0 = F0*m[0] + F2*m[2] + F0*m[4] + F6*m[6];
    const float a1 = F0*m[0] + F6*m[2] - F0*m[4] - F2*m[6];
    const float a2 = F0*m[0] - F6*m[2] - F0*m[4] + F2*m[6];
    const float a3 = F0*m[0] - F2*m[2] + F0*m[4] - F6*m[6];
    const float o0 = F1*m[1] + F3*m[3] + F5*m[5] + F7*m[7];
    const float o1 = F3*m[1] - F7*m[3] - F1*m[5] - F5*m[7];
    const float o2 = F5*m[1] - F1*m[3] + F7*m[5] + F3*m[7];
    const float o3 = F7*m[1] - F5*m[3] + F3*m[5] - F1*m[7];
    m[0] = a0 + o0; m[7] = a0 - o0;
    m[1] = a1 + o1; m[6] = a1 - o1;
    m[2] = a2 + o2; m[5] = a2 - o2;
    m[3] = a3 + o3; m[4] = a3 - o3;
}

__device__ __forceinline__ float dpp_xor8(float x) {
    // DPP row_ror:8 on 16-lane rows == lane ^ 8 (pure VALU, no lgkmcnt).
    return __builtin_bit_cast(float,
        __builtin_amdgcn_mov_dpp(__builtin_bit_cast(int, x), 0x128, 0xf, 0xf, true));
}

// 8x8 transpose across the 8 lane-groups — DS-free:
//   stage xor8  : DPP row_ror:8 + selects (VALU)
//   stage xor16 : v_permlane16_swap (1 op per register pair, both outputs)
//   stage xor32 : v_permlane32_swap
__device__ __forceinline__ void transpose8f(float m[8], int g) {
    const bool up1 = (g & 1) != 0;
#pragma unroll
    for (int j = 0; j < 8; j += 2) {
        const int jj = j | 1;
        const float yj  = dpp_xor8(m[j]);
        const float yjj = dpp_xor8(m[jj]);
        m[j]  = up1 ? yjj : m[j];
        m[jj] = up1 ? m[jj] : yj;
    }
#pragma unroll
    for (int j = 0; j < 8; ++j) {
        if ((j & 2) == 0) {
            const int jj = j | 2;
            asm("v_permlane16_swap_b32 %0, %1" : "+v"(m[j]), "+v"(m[jj]));
        }
    }
#pragma unroll
    for (int j = 0; j < 4; ++j) {
        const int jj = j | 4;
        asm("v_permlane32_swap_b32 %0, %1" : "+v"(m[j]), "+v"(m[jj]));
    }
}

// One channel: P-integer values (in[j] at column j, row g) -> reconstructed
// pixels rec[a] = out_P[g][a] (store-ready).
__device__ __forceinline__ void do_channel(const float in[8], const float* qp,
                                           const float* rqp, int g, float rec[8]) {
    float t[8];
#pragma unroll
    for (int j = 0; j < 8; ++j) t[j] = subf(in[j], 128.0f);

    fwd8(t);             // stage 1: tmp[i, k=g]
    transpose8f(t, g);   // row layout: t[k] = tmp[i=g, k]
    fwd8(t);             // stage 2: z[g, l]

    // Band-hedged quantization (band >> any accumulation-order delta).
#pragma unroll
    for (int l = 0; l < 8; ++l) {
        const float q  = qp[l];
        const float tt = mulf(t[l], rqp[l]);
        const float r  = rintf(tt);
        const float d  = subf(tt, r);
        const float dist = fabsf(fabsf(d) - 0.5f);
        const float eps = __builtin_fmaf(fabsf(tt), 8e-6f, 1.5e-5f);
        t[l] = (dist < eps) ? mulf(addf(r, copysignf(0.5f, d)), q)
                            : mulf(r, q);
    }

    // IDCT + transpose-back, from row layout t[l] = Zq[g][l]:
    //   inv -> (Zq D)[g][n];  T -> (Zq D)[j][g];
    //   inv -> (Dt Zq D)[a][g] = rec_x[a][g] = out_P[g][a].
    inv8f(t);
    transpose8f(t, g);
    inv8f(t);
#pragma unroll
    for (int j = 0; j < 8; ++j) rec[j] = t[j];
}

__global__ __launch_bounds__(256) void jpeg_k(const float* __restrict__ img,
                                              const float* __restrict__ QY,
                                              const float* __restrict__ QC,
                                              float* __restrict__ out) {
    __shared__ float lds_q[2][64];
    __shared__ float lds_rq[2][64];
    {
        const int t = threadIdx.x;
        if (t < 128) {
            const int cc = t >> 6, idx = t & 63;
            const float q = (cc ? QC : QY)[idx];
            lds_q[cc][idx]  = q;
            lds_rq[cc][idx] = divf(1.0f, q);   // exact RN(1/q), once per block
        }
    }
    __syncthreads();

    const int lane = threadIdx.x & 63;
    const int g  = lane >> 3;
    const int wv = threadIdx.x >> 6;
    const size_t plane = 1048576;  // 1024*1024
    const int row = blockIdx.y * 8 + g;
    const int col = (blockIdx.x * 4 + wv) * 64 + (lane & 7) * 8;
    const size_t base = (size_t)blockIdx.z * (3 * plane) + (size_t)row * 1024 + (size_t)col;

    const float* pR = img + base;
    const float4 r0 = *reinterpret_cast<const float4*>(pR);
    const float4 r1 = *reinterpret_cast<const float4*>(pR + 4);
    const float4 g0 = *reinterpret_cast<const float4*>(pR + plane);
    const float4 g1 = *reinterpret_cast<const float4*>(pR + plane + 4);
    const float4 b0 = *reinterpret_cast<const float4*>(pR + 2 * plane);
    const float4 b1 = *reinterpret_cast<const float4*>(pR + 2 * plane + 4);
    const float Rf[8] = {r0.x, r0.y, r0.z, r0.w, r1.x, r1.y, r1.z, r1.w};
    const float Gf[8] = {g0.x, g0.y, g0.z, g0.w, g1.x, g1.y, g1.z, g1.w};
    const float Bf[8] = {b0.x, b0.y, b0.z, b0.w, b1.x, b1.y, b1.z, b1.w};

    // Exact f32 rgb->ycbcr (literal numpy op order, rintf = RNE = np.round).
    // Must be bit-exact: integer Y/Cb/Cr feed the quant boundary decisions.
    float Yi[8], Cbi[8], Cri[8];
#pragma unroll
    for (int j = 0; j < 8; ++j) {
        const float xr = mulf(addf(mulf(Rf[j], 0.5f), 0.5f), 255.0f);
        const float xg = mulf(addf(mulf(Gf[j], 0.5f), 0.5f), 255.0f);
        const float xb = mulf(addf(mulf(Bf[j], 0.5f), 0.5f), 255.0f);
        Yi[j]  = rintf(addf(addf(addf(mulf((float)0.256788, xr), mulf((float)0.504129, xg)),
                                 mulf((float)0.0979059, xb)), 16.0f));
        Cbi[j] = rintf(addf(subf(subf(128.0f, mulf((float)0.148224, xr)),
                                 mulf((float)0.290992, xg)), mulf((float)0.439216, xb)));
        Cri[j] = rintf(subf(subf(addf(128.0f, mulf((float)0.439216, xr)),
                                 mulf((float)0.367788, xg)), mulf((float)0.0714275, xb)));
    }

    // Fully unrolled channels (no runtime-c selects / predicated writebacks).
    float rec0[8], rec1[8], rec2[8];
    do_channel(Yi,  &lds_q[0][g * 8], &lds_rq[0][g * 8], g, rec0);
    do_channel(Cbi, &lds_q[1][g * 8], &lds_rq[1][g * 8], g, rec1);
    do_channel(Cri, &lds_q[1][g * 8], &lds_rq[1][g * 8], g, rec2);

    // Fast final color stage (continuous path: 1e-7-level deviation ok).
    float fr[8], fg[8], fb[8];
    const float S = 2.0f / 255.0f;
#pragma unroll
    for (int j = 0; j < 8; ++j) {
        const float y  = rec0[j] + 112.0f;          // (+128) - 16
        const float cb = rec1[j];                    // (+128) - 128
        const float cr = rec2[j];
        const float Rv = rintf(__builtin_fmaf(1.16438f, y,
                               __builtin_fmaf(1.59603f, cr, 3.01124e-07f * cb)));
        const float Gv = rintf(__builtin_fmaf(1.16438f, y,
                               -__builtin_fmaf(0.391763f, cb, 0.812968f * cr)));
        const float Bv = rintf(__builtin_fmaf(1.16438f, y,
                               __builtin_fmaf(2.01723f, cb, 3.05426e-06f * cr)));
        fr[j] = __builtin_fmaf(Rv, S, -1.0f);
        fg[j] = __builtin_fmaf(Gv, S, -1.0f);
        fb[j] = __builtin_fmaf(Bv, S, -1.0f);
    }

    float* o = out + base;
    *reinterpret_cast<float4*>(o)                 = make_float4(fr[0], fr[1], fr[2], fr[3]);
    *reinterpret_cast<float4*>(o + 4)             = make_float4(fr[4], fr[5], fr[6], fr[7]);
    *reinterpret_cast<float4*>(o + plane)         = make_float4(fg[0], fg[1], fg[2], fg[3]);
    *reinterpret_cast<float4*>(o + plane + 4)     = make_float4(fg[4], fg[5], fg[6], fg[7]);
    *reinterpret_cast<float4*>(o + 2 * plane)     = make_float4(fb[0], fb[1], fb[2], fb[3]);
    *reinterpret_cast<float4*>(o + 2 * plane + 4) = make_float4(fb[4], fb[5], fb[6], fb[7]);
}

extern "C" void kernel_launch(void* const* d_in, const int* in_sizes, int n_in,
                              void* d_out, int out_size, void* d_ws, size_t ws_size,
                              hipStream_t stream) {
    const float* img = (const float*)d_in[0];
    const float* QY  = (const float*)d_in[1];
    const float* QC  = (const float*)d_in[2];
    float* out = (float*)d_out;
    const int B = in_sizes[0] / (3 * 1024 * 1024);
    dim3 grid(1024 / 256, 1024 / 8, B);
    jpeg_k<<<grid, dim3(256), 0, stream>>>(img, QY, QC, out);
}

// Round 17
// 46.015 us; speedup vs baseline: 5.2453x; 1.0202x over previous
//
#include <hip/hip_runtime.h>

// ---- f64 DCT magnitudes (0.5*cos(m*pi/16)); f32 casts match np.asarray(D,f32).
#define C0 0.35355339059327373
#define C1 0.49039264020161522
#define C2 0.46193976625564337
#define C3 0.41573480615127262
#define C5 0.27778511650980109
#define C6 0.19134171618254489
#define C7 0.09754516100806413

#define F0 ((float)C0)
#define F1 ((float)C1)
#define F2 ((float)C2)
#define F3 ((float)C3)
#define F5 ((float)C5)
#define F6 ((float)C6)
#define F7 ((float)C7)

// ---- exact-f32 scalar helpers (boundary-critical paths).
__device__ __forceinline__ float mulf(float a, float b) {
#pragma clang fp contract(off)
    return a * b;
}
__device__ __forceinline__ float addf(float a, float b) {
#pragma clang fp contract(off)
    return a + b;
}
__device__ __forceinline__ float subf(float a, float b) {
#pragma clang fp contract(off)
    return a - b;
}
__device__ __forceinline__ float divf(float a, float b) {
#pragma clang fp contract(off)
    return a / b;
}

// ---- forward DCT-II butterfly: m[i] <- sum_n D[i][n]*m[n]. Accumulation
// order differs from ref's chain by <= ~10 ulps -> covered by the hedge band.
__device__ __forceinline__ void fwd8(float m[8]) {
    const float e0 = m[0] + m[7], e1 = m[1] + m[6], e2 = m[2] + m[5], e3 = m[3] + m[4];
    const float o0 = m[0] - m[7], o1 = m[1] - m[6], o2 = m[2] - m[5], o3 = m[3] - m[4];
    m[0] = F0 * (e0 + e1 + e2 + e3);
    m[4] = F0 * (e0 - e1 - e2 + e3);
    m[2] = F2*e0 + F6*e1 - F6*e2 - F2*e3;
    m[6] = F6*e0 - F2*e1 + F2*e2 - F6*e3;
    m[1] = F1*o0 + F3*o1 + F5*o2 + F7*o3;
    m[3] = F3*o0 - F7*o1 - F1*o2 - F5*o3;
    m[5] = F5*o0 - F1*o1 + F7*o2 + F3*o3;
    m[7] = F7*o0 - F5*o1 + F3*o2 - F1*o3;
}

// ---- fast f32 IDCT butterfly: out[n] = sum_u D[u][n]*in[u]. Precision
// non-critical (affects only +-1-level final pixel rounding = 0.0078).
__device__ __forceinline__ void inv8f(float m[8]) {
    const float a0 = F0*m[0] + F2*m[2] + F0*m[4] + F6*m[6];
    const float a1 = F0*m[0] + F6*m[2] - F0*m[4] - F2*m[6];
    const float a2 = F0*m[0] - F6*m[2] - F0*m[4] + F2*m[6];
    const float a3 = F0*m[0] - F2*m[2] + F0*m[4] - F6*m[6];
    const float o0 = F1*m[1] + F3*m[3] + F5*m[5] + F7*m[7];
    const float o1 = F3*m[1] - F7*m[3] - F1*m[5] - F5*m[7];
    const float o2 = F5*m[1] - F1*m[3] + F7*m[5] + F3*m[7];
    const float o3 = F7*m[1] - F5*m[3] + F3*m[5] - F1*m[7];
    m[0] = a0 + o0; m[7] = a0 - o0;
    m[1] = a1 + o1; m[6] = a1 - o1;
    m[2] = a2 + o2; m[5] = a2 - o2;
    m[3] = a3 + o3; m[4] = a3 - o3;
}

__device__ __forceinline__ float dpp_xor8(float x) {
    // DPP row_ror:8 on 16-lane rows == lane ^ 8 (pure VALU, no lgkmcnt).
    return __builtin_bit_cast(float,
        __builtin_amdgcn_mov_dpp(__builtin_bit_cast(int, x), 0x128, 0xf, 0xf, true));
}

// 8x8 transpose of ALL THREE channels, stage-interleaved for cross-channel ILP.
//   stage xor8  : DPP row_ror:8 + selects (VALU)
//   stage xor16 : v_permlane16_swap (1 op per register pair, both outputs)
//   stage xor32 : v_permlane32_swap
__device__ __forceinline__ void transpose3(float m[3][8], int g) {
    const bool up1 = (g & 1) != 0;
#pragma unroll
    for (int c = 0; c < 3; ++c) {
#pragma unroll
        for (int j = 0; j < 8; j += 2) {
            const int jj = j | 1;
            const float yj  = dpp_xor8(m[c][j]);
            const float yjj = dpp_xor8(m[c][jj]);
            m[c][j]  = up1 ? yjj : m[c][j];
            m[c][jj] = up1 ? m[c][jj] : yj;
        }
    }
#pragma unroll
    for (int c = 0; c < 3; ++c) {
#pragma unroll
        for (int j = 0; j < 8; ++j) {
            if ((j & 2) == 0) {
                const int jj = j | 2;
                asm("v_permlane16_swap_b32 %0, %1" : "+v"(m[c][j]), "+v"(m[c][jj]));
            }
        }
    }
#pragma unroll
    for (int c = 0; c < 3; ++c) {
#pragma unroll
        for (int j = 0; j < 4; ++j) {
            const int jj = j | 4;
            asm("v_permlane32_swap_b32 %0, %1" : "+v"(m[c][j]), "+v"(m[c][jj]));
        }
    }
}

__global__ __launch_bounds__(256, 4) void jpeg_k(const float* __restrict__ img,
                                                 const float* __restrict__ QY,
                                                 const float* __restrict__ QC,
                                                 float* __restrict__ out) {
    __shared__ float lds_q[2][64];
    __shared__ float lds_rq[2][64];
    {
        const int t = threadIdx.x;
        if (t < 128) {
            const int cc = t >> 6, idx = t & 63;
            const float q = (cc ? QC : QY)[idx];
            lds_q[cc][idx]  = q;
            lds_rq[cc][idx] = divf(1.0f, q);   // exact RN(1/q), once per block
        }
    }
    __syncthreads();

    const int lane = threadIdx.x & 63;
    const int g  = lane >> 3;
    const int wv = threadIdx.x >> 6;
    const size_t plane = 1048576;  // 1024*1024
    const int row = blockIdx.y * 8 + g;
    const int col = (blockIdx.x * 4 + wv) * 64 + (lane & 7) * 8;
    const size_t base = (size_t)blockIdx.z * (3 * plane) + (size_t)row * 1024 + (size_t)col;

    const float* pR = img + base;
    const float4 r0 = *reinterpret_cast<const float4*>(pR);
    const float4 r1 = *reinterpret_cast<const float4*>(pR + 4);
    const float4 g0 = *reinterpret_cast<const float4*>(pR + plane);
    const float4 g1 = *reinterpret_cast<const float4*>(pR + plane + 4);
    const float4 b0 = *reinterpret_cast<const float4*>(pR + 2 * plane);
    const float4 b1 = *reinterpret_cast<const float4*>(pR + 2 * plane + 4);
    const float Rf[8] = {r0.x, r0.y, r0.z, r0.w, r1.x, r1.y, r1.z, r1.w};
    const float Gf[8] = {g0.x, g0.y, g0.z, g0.w, g1.x, g1.y, g1.z, g1.w};
    const float Bf[8] = {b0.x, b0.y, b0.z, b0.w, b1.x, b1.y, b1.z, b1.w};

    // Exact f32 rgb->ycbcr (literal numpy op order, rintf = RNE = np.round).
    // Must be bit-exact: integer Y/Cb/Cr feed the quant boundary decisions.
    // Directly produce centered values t = round(.) - 128 (Sterbenz-exact).
    float t[3][8];
#pragma unroll
    for (int j = 0; j < 8; ++j) {
        const float xr = mulf(addf(mulf(Rf[j], 0.5f), 0.5f), 255.0f);
        const float xg = mulf(addf(mulf(Gf[j], 0.5f), 0.5f), 255.0f);
        const float xb = mulf(addf(mulf(Bf[j], 0.5f), 0.5f), 255.0f);
        const float Yi  = rintf(addf(addf(addf(mulf((float)0.256788, xr), mulf((float)0.504129, xg)),
                                          mulf((float)0.0979059, xb)), 16.0f));
        const float Cbi = rintf(addf(subf(subf(128.0f, mulf((float)0.148224, xr)),
                                          mulf((float)0.290992, xg)), mulf((float)0.439216, xb)));
        const float Cri = rintf(subf(subf(addf(128.0f, mulf((float)0.439216, xr)),
                                          mulf((float)0.367788, xg)), mulf((float)0.0714275, xb)));
        t[0][j] = subf(Yi,  128.0f);
        t[1][j] = subf(Cbi, 128.0f);
        t[2][j] = subf(Cri, 128.0f);
    }

    // ---- Stage 1 (x3 interleaved): tmp[i, k=g]
#pragma unroll
    for (int c = 0; c < 3; ++c) fwd8(t[c]);
    transpose3(t, g);    // row layout: t[c][k] = tmp_c[i=g, k]
    // ---- Stage 2 (x3): z[g, l]
#pragma unroll
    for (int c = 0; c < 3; ++c) fwd8(t[c]);

    // Band-hedged quantization (band >> any accumulation-order delta).
#pragma unroll
    for (int c = 0; c < 3; ++c) {
        const int qi = (c == 0) ? 0 : 1;
        const float* qp  = &lds_q[qi][g * 8];
        const float* rqp = &lds_rq[qi][g * 8];
#pragma unroll
        for (int l = 0; l < 8; ++l) {
            const float q  = qp[l];
            const float tt = mulf(t[c][l], rqp[l]);
            const float r  = rintf(tt);
            const float d  = subf(tt, r);
            const float dist = fabsf(fabsf(d) - 0.5f);
            const float eps = __builtin_fmaf(fabsf(tt), 8e-6f, 1.5e-5f);
            t[c][l] = (dist < eps) ? mulf(addf(r, copysignf(0.5f, d)), q)
                                   : mulf(r, q);
        }
    }

    // IDCT + transpose-back, from row layout t[c][l] = Zq[g][l]:
    //   inv -> (Zq D)[g][n];  T -> (Zq D)[j][g];
    //   inv -> (Dt Zq D)[a][g] = rec_x[a][g] = out_P[g][a].   (store-ready)
#pragma unroll
    for (int c = 0; c < 3; ++c) inv8f(t[c]);
    transpose3(t, g);
#pragma unroll
    for (int c = 0; c < 3; ++c) inv8f(t[c]);

    // Fast final color stage (continuous path: 1e-7-level deviation ok).
    float fr[8], fg[8], fb[8];
    const float S = 2.0f / 255.0f;
#pragma unroll
    for (int j = 0; j < 8; ++j) {
        const float y  = t[0][j] + 112.0f;          // (+128) - 16
        const float cb = t[1][j];                    // (+128) - 128
        const float cr = t[2][j];
        const float Rv = rintf(__builtin_fmaf(1.16438f, y,
                               __builtin_fmaf(1.59603f, cr, 3.01124e-07f * cb)));
        const float Gv = rintf(__builtin_fmaf(1.16438f, y,
                               -__builtin_fmaf(0.391763f, cb, 0.812968f * cr)));
        const float Bv = rintf(__builtin_fmaf(1.16438f, y,
                               __builtin_fmaf(2.01723f, cb, 3.05426e-06f * cr)));
        fr[j] = __builtin_fmaf(Rv, S, -1.0f);
        fg[j] = __builtin_fmaf(Gv, S, -1.0f);
        fb[j] = __builtin_fmaf(Bv, S, -1.0f);
    }

    float* o = out + base;
    *reinterpret_cast<float4*>(o)                 = make_float4(fr[0], fr[1], fr[2], fr[3]);
    *reinterpret_cast<float4*>(o + 4)             = make_float4(fr[4], fr[5], fr[6], fr[7]);
    *reinterpret_cast<float4*>(o + plane)         = make_float4(fg[0], fg[1], fg[2], fg[3]);
    *reinterpret_cast<float4*>(o + plane + 4)     = make_float4(fg[4], fg[5], fg[6], fg[7]);
    *reinterpret_cast<float4*>(o + 2 * plane)     = make_float4(fb[0], fb[1], fb[2], fb[3]);
    *reinterpret_cast<float4*>(o + 2 * plane + 4) = make_float4(fb[4], fb[5], fb[6], fb[7]);
}

extern "C" void kernel_launch(void* const* d_in, const int* in_sizes, int n_in,
                              void* d_out, int out_size, void* d_ws, size_t ws_size,
                              hipStream_t stream) {
    const float* img = (const float*)d_in[0];
    const float* QY  = (const float*)d_in[1];
    const float* QC  = (const float*)d_in[2];
    float* out = (float*)d_out;
    const int B = in_sizes[0] / (3 * 1024 * 1024);
    dim3 grid(1024 / 256, 1024 / 8, B);
    jpeg_k<<<grid, dim3(256), 0, stream>>>(img, QY, QC, out);
}